// Round 3
// baseline (243.079 us; speedup 1.0000x reference)
//
#include <hip/hip_runtime.h>
#include <hip/hip_bf16.h>
#include <hip/hip_fp16.h>
#include <cstdint>
#include <cstddef>

#define NB 8
#define TT 1024
#define DD 512
#define HH 8
#define DHD 64

using bf16x8 = __attribute__((ext_vector_type(8))) short;
using f32x4  = __attribute__((ext_vector_type(4))) float;

#define MFMA(a, b, c) __builtin_amdgcn_mfma_f32_16x16x32_bf16((a), (b), (c), 0, 0, 0)

__device__ __forceinline__ short f2bf(float f) {
  union { float f; uint32_t u; } x; x.f = f;
  uint32_t r = x.u + 0x7fffu + ((x.u >> 16) & 1u);
  return (short)(r >> 16);
}

// ---------------- weight transpose + f32->bf16 ----------------
__global__ __launch_bounds__(256) void kt_transpose(
    const float* __restrict__ W0, const float* __restrict__ W1,
    const float* __restrict__ W2, const float* __restrict__ W3,
    short* __restrict__ WT)
{
  __shared__ float tile[32][33];
  int z = blockIdx.z;
  const float* W = (z == 0) ? W0 : (z == 1) ? W1 : (z == 2) ? W2 : W3;
  short* out = WT + (size_t)z * DD * DD;
  int tx = threadIdx.x, ty = threadIdx.y;  // (32, 8)
  int bx = blockIdx.x * 32, by = blockIdx.y * 32;
#pragma unroll
  for (int kq = 0; kq < 4; ++kq)
    tile[ty + kq * 8][tx] = W[(size_t)(by + ty + kq * 8) * DD + bx + tx];
  __syncthreads();
#pragma unroll
  for (int kq = 0; kq < 4; ++kq)
    out[(size_t)(bx + ty + kq * 8) * DD + by + tx] = f2bf(tile[tx][ty + kq * 8]);
}

// ---------------- QKV projection GEMM ----------------
// z: 0=Q (scaled by 1/8, layout [N,H,T,64]), 1=K ([N,H,T,64]), 2=V ([N,H,64,T])
__global__ __launch_bounds__(256) void kt_proj(
    const float* __restrict__ Xq, const float* __restrict__ Xk, const float* __restrict__ Xv,
    const short* __restrict__ WTall,
    const float* __restrict__ bq, const float* __restrict__ bk, const float* __restrict__ bv,
    short* __restrict__ qb, short* __restrict__ kb, short* __restrict__ vT)
{
  int z = blockIdx.z;
  const float* X    = (z == 0) ? Xq : (z == 1) ? Xk : Xv;
  const short* WT   = WTall + (size_t)z * DD * DD;
  const float* bias = (z == 0) ? bq : (z == 1) ? bk : bv;
  short* out        = (z == 0) ? qb : (z == 1) ? kb : vT;

  __shared__ alignas(16) short As[64][40];
  __shared__ alignas(16) short Bs[64][40];
  int tid = threadIdx.x;
  int w = tid >> 6, lane = tid & 63, g = lane >> 4, c16 = lane & 15;
  int m0 = blockIdx.x * 64, c0 = blockIdx.y * 64;
  int srow = tid >> 2, skg = (tid & 3) * 8;
  f32x4 acc[4] = {};

  for (int kk = 0; kk < DD; kk += 32) {
    const float* ap = X + (size_t)(m0 + srow) * DD + kk + skg;
    float4 a0 = *(const float4*)ap;
    float4 a1 = *(const float4*)(ap + 4);
    bf16x8 av;
    av[0] = f2bf(a0.x); av[1] = f2bf(a0.y); av[2] = f2bf(a0.z); av[3] = f2bf(a0.w);
    av[4] = f2bf(a1.x); av[5] = f2bf(a1.y); av[6] = f2bf(a1.z); av[7] = f2bf(a1.w);
    *(bf16x8*)&As[srow][skg] = av;
    *(bf16x8*)&Bs[srow][skg] = *(const bf16x8*)(WT + (size_t)(c0 + srow) * DD + kk + skg);
    __syncthreads();
    bf16x8 af = *(const bf16x8*)&As[w * 16 + c16][g * 8];
#pragma unroll
    for (int ct = 0; ct < 4; ++ct) {
      bf16x8 bfv = *(const bf16x8*)&Bs[ct * 16 + c16][g * 8];
      acc[ct] = MFMA(af, bfv, acc[ct]);
    }
    __syncthreads();
  }

#pragma unroll
  for (int ct = 0; ct < 4; ++ct) {
    int c = c0 + ct * 16 + c16;
    float bv_ = bias[c];
    int hh = c >> 6, dh = c & 63;
#pragma unroll
    for (int r = 0; r < 4; ++r) {
      int m = m0 + w * 16 + g * 4 + r;
      int n = m >> 10, t = m & 1023;
      float val = acc[ct][r] + bv_;
      if (z == 0) val *= 0.125f;  // fold score scaling into q
      size_t addr = (z < 2)
          ? ((((size_t)n * HH + hh) * TT + t) * DHD + dh)     // q,k: [N,H,T,64]
          : ((((size_t)n * HH + hh) * DHD + dh) * TT + t);    // v : [N,H,64,T]
      out[addr] = f2bf(val);
    }
  }
}

// ---------------- output projection GEMM ----------------
__global__ __launch_bounds__(256) void kt_outproj(
    const short* __restrict__ A, const short* __restrict__ WT,
    const float* __restrict__ bias, float* __restrict__ out)
{
  __shared__ alignas(16) short As[64][40];
  __shared__ alignas(16) short Bs[64][40];
  int tid = threadIdx.x;
  int w = tid >> 6, lane = tid & 63, g = lane >> 4, c16 = lane & 15;
  int m0 = blockIdx.x * 64, c0 = blockIdx.y * 64;
  int srow = tid >> 2, skg = (tid & 3) * 8;
  f32x4 acc[4] = {};

  for (int kk = 0; kk < DD; kk += 32) {
    *(bf16x8*)&As[srow][skg] = *(const bf16x8*)(A + (size_t)(m0 + srow) * DD + kk + skg);
    *(bf16x8*)&Bs[srow][skg] = *(const bf16x8*)(WT + (size_t)(c0 + srow) * DD + kk + skg);
    __syncthreads();
    bf16x8 af = *(const bf16x8*)&As[w * 16 + c16][g * 8];
#pragma unroll
    for (int ct = 0; ct < 4; ++ct) {
      bf16x8 bfv = *(const bf16x8*)&Bs[ct * 16 + c16][g * 8];
      acc[ct] = MFMA(af, bfv, acc[ct]);
    }
    __syncthreads();
  }

#pragma unroll
  for (int ct = 0; ct < 4; ++ct) {
    int c = c0 + ct * 16 + c16;
    float bv_ = bias[c];
#pragma unroll
    for (int r = 0; r < 4; ++r) {
      int m = m0 + w * 16 + g * 4 + r;
      out[(size_t)m * DD + c] = acc[ct][r] + bv_;
    }
  }
}

// ---------------- fused attention, v4 ----------------
// Same schedule as v3 (8 waves, per-wave 128-k slice, single-barrier softmax,
// 2 barriers/head). Change: pbuf and outred UNION into one per-wave 4352-B
// LDS region (disjoint lifetimes within a wave). LDS 69.6 -> 35 KB so two
// 512-thread blocks fit per CU (effective LDS pool ~128 KB; v3's 68 KB
// limited residency to 1 block -> 22% occupancy).
__global__ __launch_bounds__(512, 2) void kt_attn(
    const short* __restrict__ qbuf, const short* __restrict__ kbuf, const short* __restrict__ vT,
    const float* __restrict__ segms, const int* __restrict__ mask,
    short* __restrict__ attn, float* __restrict__ pmean)
{
  int bx = blockIdx.x;
  int n = bx & 7, qt = bx >> 3;          // XCD-local batch: all blocks of n on XCD n
  int tid = threadIdx.x, w = tid >> 6, lane = tid & 63, g = lane >> 4, c16 = lane & 15;
  int kw = w * 128;

  // per-wave union region: pbuf short[16][136] (4352 B)  |  outred float[16][66] (4224 B)
  __shared__ alignas(16) char uni[8][4352];
  __shared__ alignas(16) float red_m[8][16];
  __shared__ alignas(16) float red_s[8][16];
  short (*pbuf)[136] = (short (*)[136])uni[w];
  float (*outw)[66]  = (float (*)[66])uni[w];

  // ---- hoist mask bits + segms (fp16 packed); h-invariant ----
  unsigned mm = 0u;
  uint32_t sgp[4][4];
  float pm[4][8];
#pragma unroll
  for (int r = 0; r < 4; ++r) {
    uint32_t base = ((uint32_t)(n * TT) + qt * 16 + g * 4 + r) * TT + kw + c16;
#pragma unroll
    for (int ct = 0; ct < 8; ct += 2) {
      if (mask[base + ct * 16])      mm |= 1u << (r * 8 + ct);
      if (mask[base + ct * 16 + 16]) mm |= 1u << (r * 8 + ct + 1);
      float s0 = segms[base + ct * 16], s1 = segms[base + ct * 16 + 16];
      sgp[r][ct >> 1] = (uint32_t)__half_as_ushort(__float2half(s0))
                      | ((uint32_t)__half_as_ushort(__float2half(s1)) << 16);
      pm[r][ct] = 0.f; pm[r][ct + 1] = 0.f;
    }
  }

  for (int h = 0; h < HH; ++h) {
    const short* qp = qbuf + ((((size_t)n * HH + h) * TT) + qt * 16) * DHD;
    const short* kp = kbuf + (((size_t)n * HH + h) * TT) * DHD;
    const short* vp = vT   + (((size_t)n * HH + h) * DHD) * TT;

    bf16x8 aq0 = *(const bf16x8*)(qp + c16 * DHD + g * 8);
    bf16x8 aq1 = *(const bf16x8*)(qp + c16 * DHD + g * 8 + 32);

    // ---- QK^T over this wave's 128-k slice (q pre-scaled by 1/8) ----
    f32x4 sc[8];
    __builtin_amdgcn_s_setprio(1);
#pragma unroll
    for (int ct = 0; ct < 8; ++ct) {
      const short* kpp = kp + (size_t)(kw + ct * 16 + c16) * DHD + g * 8;
      f32x4 a = {};
      a = MFMA(aq0, *(const bf16x8*)kpp, a);
      a = MFMA(aq1, *(const bf16x8*)(kpp + 32), a);
      sc[ct] = a;
    }
    __builtin_amdgcn_s_setprio(0);

    // ---- mask + wave-local row max ----
    float mx[4] = {-3e38f, -3e38f, -3e38f, -3e38f};
#pragma unroll
    for (int r = 0; r < 4; ++r)
#pragma unroll
      for (int ct = 0; ct < 8; ++ct) {
        float s = ((mm >> (r * 8 + ct)) & 1u) ? sc[ct][r] : -1e9f;
        sc[ct][r] = s;
        mx[r] = fmaxf(mx[r], s);
      }
#pragma unroll
    for (int r = 0; r < 4; ++r) {
      mx[r] = fmaxf(mx[r], __shfl_xor(mx[r], 1, 16));
      mx[r] = fmaxf(mx[r], __shfl_xor(mx[r], 2, 16));
      mx[r] = fmaxf(mx[r], __shfl_xor(mx[r], 4, 16));
      mx[r] = fmaxf(mx[r], __shfl_xor(mx[r], 8, 16));
    }

    // ---- exp with LOCAL max (p<=1 safe) + wave-local sum ----
    float sm[4] = {0.f, 0.f, 0.f, 0.f};
#pragma unroll
    for (int ct = 0; ct < 8; ++ct)
#pragma unroll
      for (int r = 0; r < 4; ++r) {
        float p = __expf(sc[ct][r] - mx[r]);
        sc[ct][r] = p;
        sm[r] += p;
      }
#pragma unroll
    for (int r = 0; r < 4; ++r) {
      sm[r] += __shfl_xor(sm[r], 1, 16);
      sm[r] += __shfl_xor(sm[r], 2, 16);
      sm[r] += __shfl_xor(sm[r], 4, 16);
      sm[r] += __shfl_xor(sm[r], 8, 16);
    }
    if (c16 == 0) {
#pragma unroll
      for (int r = 0; r < 4; ++r) {
        red_m[w][g * 4 + r] = mx[r];
        red_s[w][g * 4 + r] = sm[r];
      }
    }
    __syncthreads();  // barrier A: (m,S) ready; fences prev head's outred reads vs pbuf writes

    // ---- combine: scale_w = exp(m_w - m*) / Z  (vectorized LDS reads) ----
    float msx[4] = {-3e38f, -3e38f, -3e38f, -3e38f};
#pragma unroll
    for (int wi = 0; wi < 8; ++wi) {
      f32x4 v = *(const f32x4*)&red_m[wi][g * 4];
#pragma unroll
      for (int r = 0; r < 4; ++r) msx[r] = fmaxf(msx[r], v[r]);
    }
    float Z[4] = {0.f, 0.f, 0.f, 0.f};
#pragma unroll
    for (int wi = 0; wi < 8; ++wi) {
      f32x4 vm = *(const f32x4*)&red_m[wi][g * 4];
      f32x4 vs = *(const f32x4*)&red_s[wi][g * 4];
#pragma unroll
      for (int r = 0; r < 4; ++r) Z[r] += vs[r] * __expf(vm[r] - msx[r]);
    }
    float scl[4];
#pragma unroll
    for (int r = 0; r < 4; ++r) scl[r] = __expf(mx[r] - msx[r]) / Z[r];

    // ---- probs = p*scale*segms ; accumulate pmean ; stash bf16 (own slice) ----
#pragma unroll
    for (int r = 0; r < 4; ++r)
#pragma unroll
      for (int ct = 0; ct < 8; ++ct) {
        float seg = __half2float(__ushort_as_half(
            (unsigned short)(sgp[r][ct >> 1] >> ((ct & 1) * 16))));
        float pr = sc[ct][r] * scl[r] * seg;
        pm[r][ct] += pr;
        pbuf[g * 4 + r][ct * 16 + c16] = f2bf(pr);
      }
    // no barrier: pbuf slice is wave-private (same-wave ds ordering)

    // ---- PV over this wave's 128-k slice ----
    f32x4 oa[4] = {};
    __builtin_amdgcn_s_setprio(1);
#pragma unroll
    for (int ks = 0; ks < 4; ++ks) {
      bf16x8 pa = *(const bf16x8*)&pbuf[c16][ks * 32 + g * 8];
#pragma unroll
      for (int ct = 0; ct < 4; ++ct) {
        const short* vpp = vp + (size_t)(ct * 16 + c16) * TT + kw + ks * 32 + g * 8;
        oa[ct] = MFMA(pa, *(const bf16x8*)vpp, oa[ct]);
      }
    }
    __builtin_amdgcn_s_setprio(0);

    // overwrite own (dead) pbuf region with PV partials — wave-private, no barrier
#pragma unroll
    for (int ct = 0; ct < 4; ++ct)
#pragma unroll
      for (int r = 0; r < 4; ++r)
        outw[g * 4 + r][ct * 16 + c16] = oa[ct][r];
    __syncthreads();  // barrier C: all outred ready

    // ---- cross-wave reduce (8 partials) + write attn[n][t][h*64+d] ----
    {
      int q = tid >> 5, dg = (tid & 31) * 2;
      float v0 = 0.f, v1 = 0.f;
#pragma unroll
      for (int wi = 0; wi < 8; ++wi) {
        const float* op = (const float*)uni[wi];
        v0 += op[q * 66 + dg];
        v1 += op[q * 66 + dg + 1];
      }
      ushort2 st;
      st.x = (unsigned short)f2bf(v0);
      st.y = (unsigned short)f2bf(v1);
      *(ushort2*)(attn + ((size_t)(n * TT) + qt * 16 + q) * DD + h * DHD + dg) = st;
    }
    // next head's pbuf writes are fenced by barrier A of that head
  }

  // ---- write probs mean (1/H) ----
#pragma unroll
  for (int r = 0; r < 4; ++r) {
    uint32_t base = ((uint32_t)(n * TT) + qt * 16 + g * 4 + r) * TT + kw + c16;
#pragma unroll
    for (int ct = 0; ct < 8; ++ct)
      pmean[base + ct * 16] = pm[r][ct] * 0.125f;
  }
}

extern "C" void kernel_launch(void* const* d_in, const int* in_sizes, int n_in,
                              void* d_out, int out_size, void* d_ws, size_t ws_size,
                              hipStream_t stream) {
  const float* query = (const float*)d_in[0];
  const float* key_  = (const float*)d_in[1];
  const float* value = (const float*)d_in[2];
  const float* segms = (const float*)d_in[3];
  const int*   mask  = (const int*)d_in[4];
  const float* Wq = (const float*)d_in[5];
  const float* bq = (const float*)d_in[6];
  const float* Wk = (const float*)d_in[7];
  const float* bk = (const float*)d_in[8];
  const float* Wv = (const float*)d_in[9];
  const float* bv = (const float*)d_in[10];
  const float* Wo = (const float*)d_in[11];
  const float* bo = (const float*)d_in[12];

  char* ws = (char*)d_ws;
  short* WT   = (short*)(ws);                        // 4 x 512x512 bf16 = 2 MB
  short* qb   = (short*)(ws + ((size_t)2  << 20));   // [N,H,T,64] bf16 = 8 MB
  short* kb   = (short*)(ws + ((size_t)10 << 20));   // [N,H,T,64] bf16 = 8 MB
  short* vT   = (short*)(ws + ((size_t)18 << 20));   // [N,H,64,T] bf16 = 8 MB
  short* attn = (short*)(ws + ((size_t)26 << 20));   // [N,T,D]   bf16 = 8 MB
  float* outp  = (float*)d_out;
  float* pmean = outp + (size_t)NB * TT * DD;

  kt_transpose<<<dim3(16, 16, 4), dim3(32, 8), 0, stream>>>(Wq, Wk, Wv, Wo, WT);
  kt_proj<<<dim3(128, 8, 3), 256, 0, stream>>>(query, key_, value, WT, bq, bk, bv, qb, kb, vT);
  kt_attn<<<dim3(512), dim3(512), 0, stream>>>(qb, kb, vT, segms, mask, attn, pmean);
  kt_outproj<<<dim3(128, 8), 256, 0, stream>>>(attn, WT + (size_t)3 * DD * DD, bo, outp);
}

// Round 4
// 229.763 us; speedup vs baseline: 1.0580x; 1.0580x over previous
//
#include <hip/hip_runtime.h>
#include <hip/hip_bf16.h>
#include <hip/hip_fp16.h>
#include <cstdint>
#include <cstddef>

#define NB 8
#define TT 1024
#define DD 512
#define HH 8
#define DHD 64

using bf16x8 = __attribute__((ext_vector_type(8))) short;
using f32x4  = __attribute__((ext_vector_type(4))) float;

#define MFMA(a, b, c) __builtin_amdgcn_mfma_f32_16x16x32_bf16((a), (b), (c), 0, 0, 0)

__device__ __forceinline__ short f2bf(float f) {
  union { float f; uint32_t u; } x; x.f = f;
  uint32_t r = x.u + 0x7fffu + ((x.u >> 16) & 1u);
  return (short)(r >> 16);
}

// pack two floats into two bf16 (round-nearest-even) in one u32
__device__ __forceinline__ uint32_t pkbf(float a, float b) {
  union { float f; uint32_t u; } x, y; x.f = a; y.f = b;
  uint32_t ra = x.u + 0x7fffu + ((x.u >> 16) & 1u);
  uint32_t rb = y.u + 0x7fffu + ((y.u >> 16) & 1u);
  return (ra >> 16) | (rb & 0xffff0000u);
}

// ---------------- weight transpose + f32->bf16 ----------------
__global__ __launch_bounds__(256) void kt_transpose(
    const float* __restrict__ W0, const float* __restrict__ W1,
    const float* __restrict__ W2, const float* __restrict__ W3,
    short* __restrict__ WT)
{
  __shared__ float tile[32][33];
  int z = blockIdx.z;
  const float* W = (z == 0) ? W0 : (z == 1) ? W1 : (z == 2) ? W2 : W3;
  short* out = WT + (size_t)z * DD * DD;
  int tx = threadIdx.x, ty = threadIdx.y;  // (32, 8)
  int bx = blockIdx.x * 32, by = blockIdx.y * 32;
#pragma unroll
  for (int kq = 0; kq < 4; ++kq)
    tile[ty + kq * 8][tx] = W[(size_t)(by + ty + kq * 8) * DD + bx + tx];
  __syncthreads();
#pragma unroll
  for (int kq = 0; kq < 4; ++kq)
    out[(size_t)(bx + ty + kq * 8) * DD + by + tx] = f2bf(tile[tx][ty + kq * 8]);
}

// ---------------- QKV projection GEMM ----------------
// z: 0=Q (scaled by 1/8, layout [N,H,T,64]), 1=K ([N,H,T,64]), 2=V ([N,H,64,T])
__global__ __launch_bounds__(256) void kt_proj(
    const float* __restrict__ Xq, const float* __restrict__ Xk, const float* __restrict__ Xv,
    const short* __restrict__ WTall,
    const float* __restrict__ bq, const float* __restrict__ bk, const float* __restrict__ bv,
    short* __restrict__ qb, short* __restrict__ kb, short* __restrict__ vT)
{
  int z = blockIdx.z;
  const float* X    = (z == 0) ? Xq : (z == 1) ? Xk : Xv;
  const short* WT   = WTall + (size_t)z * DD * DD;
  const float* bias = (z == 0) ? bq : (z == 1) ? bk : bv;
  short* out        = (z == 0) ? qb : (z == 1) ? kb : vT;

  __shared__ alignas(16) short As[64][40];
  __shared__ alignas(16) short Bs[64][40];
  int tid = threadIdx.x;
  int w = tid >> 6, lane = tid & 63, g = lane >> 4, c16 = lane & 15;
  int m0 = blockIdx.x * 64, c0 = blockIdx.y * 64;
  int srow = tid >> 2, skg = (tid & 3) * 8;
  f32x4 acc[4] = {};

  for (int kk = 0; kk < DD; kk += 32) {
    const float* ap = X + (size_t)(m0 + srow) * DD + kk + skg;
    float4 a0 = *(const float4*)ap;
    float4 a1 = *(const float4*)(ap + 4);
    bf16x8 av;
    av[0] = f2bf(a0.x); av[1] = f2bf(a0.y); av[2] = f2bf(a0.z); av[3] = f2bf(a0.w);
    av[4] = f2bf(a1.x); av[5] = f2bf(a1.y); av[6] = f2bf(a1.z); av[7] = f2bf(a1.w);
    *(bf16x8*)&As[srow][skg] = av;
    *(bf16x8*)&Bs[srow][skg] = *(const bf16x8*)(WT + (size_t)(c0 + srow) * DD + kk + skg);
    __syncthreads();
    bf16x8 af = *(const bf16x8*)&As[w * 16 + c16][g * 8];
#pragma unroll
    for (int ct = 0; ct < 4; ++ct) {
      bf16x8 bfv = *(const bf16x8*)&Bs[ct * 16 + c16][g * 8];
      acc[ct] = MFMA(af, bfv, acc[ct]);
    }
    __syncthreads();
  }

#pragma unroll
  for (int ct = 0; ct < 4; ++ct) {
    int c = c0 + ct * 16 + c16;
    float bv_ = bias[c];
    int hh = c >> 6, dh = c & 63;
#pragma unroll
    for (int r = 0; r < 4; ++r) {
      int m = m0 + w * 16 + g * 4 + r;
      int n = m >> 10, t = m & 1023;
      float val = acc[ct][r] + bv_;
      if (z == 0) val *= 0.125f;  // fold score scaling into q
      size_t addr = (z < 2)
          ? ((((size_t)n * HH + hh) * TT + t) * DHD + dh)     // q,k: [N,H,T,64]
          : ((((size_t)n * HH + hh) * DHD + dh) * TT + t);    // v : [N,H,64,T]
      out[addr] = f2bf(val);
    }
  }
}

// ---------------- output projection GEMM ----------------
__global__ __launch_bounds__(256) void kt_outproj(
    const short* __restrict__ A, const short* __restrict__ WT,
    const float* __restrict__ bias, float* __restrict__ out)
{
  __shared__ alignas(16) short As[64][40];
  __shared__ alignas(16) short Bs[64][40];
  int tid = threadIdx.x;
  int w = tid >> 6, lane = tid & 63, g = lane >> 4, c16 = lane & 15;
  int m0 = blockIdx.x * 64, c0 = blockIdx.y * 64;
  int srow = tid >> 2, skg = (tid & 3) * 8;
  f32x4 acc[4] = {};

  for (int kk = 0; kk < DD; kk += 32) {
    *(bf16x8*)&As[srow][skg] = *(const bf16x8*)(A + (size_t)(m0 + srow) * DD + kk + skg);
    *(bf16x8*)&Bs[srow][skg] = *(const bf16x8*)(WT + (size_t)(c0 + srow) * DD + kk + skg);
    __syncthreads();
    bf16x8 af = *(const bf16x8*)&As[w * 16 + c16][g * 8];
#pragma unroll
    for (int ct = 0; ct < 4; ++ct) {
      bf16x8 bfv = *(const bf16x8*)&Bs[ct * 16 + c16][g * 8];
      acc[ct] = MFMA(af, bfv, acc[ct]);
    }
    __syncthreads();
  }

#pragma unroll
  for (int ct = 0; ct < 4; ++ct) {
    int c = c0 + ct * 16 + c16;
    float bv_ = bias[c];
#pragma unroll
    for (int r = 0; r < 4; ++r) {
      int m = m0 + w * 16 + g * 4 + r;
      out[(size_t)m * DD + c] = acc[ct][r] + bv_;
    }
  }
}

// ---------------- fused attention, v5 ----------------
// Same macrostructure as v4 (8 waves x 128-k slice, union LDS, 2 barriers/head).
// Change: SWAPPED QK^T  ->  MFMA(K, Q): output lane layout q=c16, k in-lane
// (kw + ct*16 + g*4 + r). Row max/sum become in-lane + 2 shuffles (was 32
// ds_swizzles/head); pbuf writes 8x b64 (was 32x b16); combine via transposed
// red_mT -> 4x b128; mask/segms/pmean vectorized int4/float4.
// Head order staggered per qt to decorrelate same-line L2 bursts.
__global__ __launch_bounds__(512, 2) void kt_attn(
    const short* __restrict__ qbuf, const short* __restrict__ kbuf, const short* __restrict__ vT,
    const float* __restrict__ segms, const int* __restrict__ mask,
    short* __restrict__ attn, float* __restrict__ pmean)
{
  int bx = blockIdx.x;
  int n = bx & 7, qt = bx >> 3;          // XCD-local batch
  int tid = threadIdx.x, w = tid >> 6, lane = tid & 63, g = lane >> 4, c16 = lane & 15;
  int kw = w * 128;

  // per-wave union region: pbuf short[16][136] (4352 B) | outred float[16][66] (4224 B)
  __shared__ alignas(16) char uni[8][4352];
  __shared__ alignas(16) float red_mT[16][8];
  __shared__ alignas(16) float red_sT[16][8];
  short (*pbuf)[136] = (short (*)[136])uni[w];
  float (*outw)[66]  = (float (*)[66])uni[w];

  // ---- hoist mask bits + segms (fp16 packed); h-invariant; vectorized ----
  // lane owns q-row (qt*16 + c16), k-cols kw + ct*16 + g*4 + {0..3}
  unsigned mm = 0u;
  __half2 sgp[8][2];
  float pm[8][4];
  uint32_t rowbase = ((uint32_t)(n * TT) + qt * 16 + c16) * TT + kw + g * 4;
#pragma unroll
  for (int ct = 0; ct < 8; ++ct) {
    int4   mv = *(const int4*)  &mask [rowbase + ct * 16];
    float4 sg = *(const float4*)&segms[rowbase + ct * 16];
    if (mv.x) mm |= 1u << (ct * 4 + 0);
    if (mv.y) mm |= 1u << (ct * 4 + 1);
    if (mv.z) mm |= 1u << (ct * 4 + 2);
    if (mv.w) mm |= 1u << (ct * 4 + 3);
    sgp[ct][0] = __floats2half2_rn(sg.x, sg.y);
    sgp[ct][1] = __floats2half2_rn(sg.z, sg.w);
    pm[ct][0] = 0.f; pm[ct][1] = 0.f; pm[ct][2] = 0.f; pm[ct][3] = 0.f;
  }

  for (int hh = 0; hh < HH; ++hh) {
    int h = (hh + qt) & 7;  // stagger heads across blocks
    const short* qp = qbuf + ((((size_t)n * HH + h) * TT) + qt * 16) * DHD;
    const short* kp = kbuf + (((size_t)n * HH + h) * TT) * DHD;
    const short* vp = vT   + (((size_t)n * HH + h) * DHD) * TT;

    bf16x8 aq0 = *(const bf16x8*)(qp + c16 * DHD + g * 8);
    bf16x8 aq1 = *(const bf16x8*)(qp + c16 * DHD + g * 8 + 32);

    // ---- swapped QK^T: sc[ct][r] = S(q = c16, k = kw + ct*16 + g*4 + r) ----
    f32x4 sc[8];
    __builtin_amdgcn_s_setprio(1);
#pragma unroll
    for (int ct = 0; ct < 8; ++ct) {
      const short* kpp = kp + (size_t)(kw + ct * 16 + c16) * DHD + g * 8;
      f32x4 a = {};
      a = MFMA(*(const bf16x8*)kpp, aq0, a);
      a = MFMA(*(const bf16x8*)(kpp + 32), aq1, a);
      sc[ct] = a;
    }
    __builtin_amdgcn_s_setprio(0);

    // ---- mask + in-lane row max + 2 shuffles ----
    float mx = -3e38f;
#pragma unroll
    for (int ct = 0; ct < 8; ++ct)
#pragma unroll
      for (int r = 0; r < 4; ++r) {
        float s = ((mm >> (ct * 4 + r)) & 1u) ? sc[ct][r] : -1e9f;
        sc[ct][r] = s;
        mx = fmaxf(mx, s);
      }
    mx = fmaxf(mx, __shfl_xor(mx, 16));
    mx = fmaxf(mx, __shfl_xor(mx, 32));

    // ---- exp with wave-local max (p<=1 safe) + in-lane sum + 2 shuffles ----
    float sm = 0.f;
#pragma unroll
    for (int ct = 0; ct < 8; ++ct)
#pragma unroll
      for (int r = 0; r < 4; ++r) {
        float p = __expf(sc[ct][r] - mx);
        sc[ct][r] = p;
        sm += p;
      }
    sm += __shfl_xor(sm, 16);
    sm += __shfl_xor(sm, 32);
    if (lane < 16) {
      red_mT[c16][w] = mx;
      red_sT[c16][w] = sm;
    }
    __syncthreads();  // barrier A: (m,S) ready; fences prev head's outw reads vs pbuf writes

    // ---- combine: scale_w = exp(m_w - m*) / Z ----
    f32x4 vm0 = *(const f32x4*)&red_mT[c16][0];
    f32x4 vm1 = *(const f32x4*)&red_mT[c16][4];
    f32x4 vs0 = *(const f32x4*)&red_sT[c16][0];
    f32x4 vs1 = *(const f32x4*)&red_sT[c16][4];
    float ms = fmaxf(fmaxf(fmaxf(vm0[0], vm0[1]), fmaxf(vm0[2], vm0[3])),
                     fmaxf(fmaxf(vm1[0], vm1[1]), fmaxf(vm1[2], vm1[3])));
    float Z = vs0[0] * __expf(vm0[0] - ms) + vs0[1] * __expf(vm0[1] - ms)
            + vs0[2] * __expf(vm0[2] - ms) + vs0[3] * __expf(vm0[3] - ms)
            + vs1[0] * __expf(vm1[0] - ms) + vs1[1] * __expf(vm1[1] - ms)
            + vs1[2] * __expf(vm1[2] - ms) + vs1[3] * __expf(vm1[3] - ms);
    float scl = __expf(mx - ms) / Z;

    // ---- probs = p*scale*segms ; accumulate pmean ; stash packed b64 ----
#pragma unroll
    for (int ct = 0; ct < 8; ++ct) {
      float2 s01 = __half22float2(sgp[ct][0]);
      float2 s23 = __half22float2(sgp[ct][1]);
      float p0 = sc[ct][0] * scl * s01.x;
      float p1 = sc[ct][1] * scl * s01.y;
      float p2 = sc[ct][2] * scl * s23.x;
      float p3 = sc[ct][3] * scl * s23.y;
      pm[ct][0] += p0; pm[ct][1] += p1; pm[ct][2] += p2; pm[ct][3] += p3;
      uint2 pk; pk.x = pkbf(p0, p1); pk.y = pkbf(p2, p3);
      *(uint2*)&pbuf[c16][ct * 16 + g * 4] = pk;
    }
    // no barrier: pbuf slice is wave-private (same-wave ds ordering)

    // ---- PV over this wave's 128-k slice ----
    f32x4 oa[4] = {};
    __builtin_amdgcn_s_setprio(1);
#pragma unroll
    for (int ks = 0; ks < 4; ++ks) {
      bf16x8 pa = *(const bf16x8*)&pbuf[c16][ks * 32 + g * 8];
#pragma unroll
      for (int ct = 0; ct < 4; ++ct) {
        const short* vpp = vp + (size_t)(ct * 16 + c16) * TT + kw + ks * 32 + g * 8;
        oa[ct] = MFMA(pa, *(const bf16x8*)vpp, oa[ct]);
      }
    }
    __builtin_amdgcn_s_setprio(0);

    // overwrite own (dead) pbuf region with PV partials — wave-private
#pragma unroll
    for (int ct = 0; ct < 4; ++ct)
#pragma unroll
      for (int r = 0; r < 4; ++r)
        outw[g * 4 + r][ct * 16 + c16] = oa[ct][r];
    __syncthreads();  // barrier C: all partials ready

    // ---- cross-wave reduce (8 partials) + write attn[n][t][h*64+d] ----
    {
      int q = tid >> 5, dg = (tid & 31) * 2;
      float v0 = 0.f, v1 = 0.f;
#pragma unroll
      for (int wi = 0; wi < 8; ++wi) {
        float2 rd = *(const float2*)((const float*)uni[wi] + q * 66 + dg);
        v0 += rd.x;
        v1 += rd.y;
      }
      ushort2 st;
      st.x = (unsigned short)f2bf(v0);
      st.y = (unsigned short)f2bf(v1);
      *(ushort2*)(attn + ((size_t)(n * TT) + qt * 16 + q) * DD + h * DHD + dg) = st;
    }
    // next head's pbuf writes are fenced by barrier A of that head
  }

  // ---- write probs mean (1/H), vectorized float4 ----
#pragma unroll
  for (int ct = 0; ct < 8; ++ct) {
    float4 o;
    o.x = pm[ct][0] * 0.125f; o.y = pm[ct][1] * 0.125f;
    o.z = pm[ct][2] * 0.125f; o.w = pm[ct][3] * 0.125f;
    *(float4*)&pmean[rowbase + ct * 16] = o;
  }
}

extern "C" void kernel_launch(void* const* d_in, const int* in_sizes, int n_in,
                              void* d_out, int out_size, void* d_ws, size_t ws_size,
                              hipStream_t stream) {
  const float* query = (const float*)d_in[0];
  const float* key_  = (const float*)d_in[1];
  const float* value = (const float*)d_in[2];
  const float* segms = (const float*)d_in[3];
  const int*   mask  = (const int*)d_in[4];
  const float* Wq = (const float*)d_in[5];
  const float* bq = (const float*)d_in[6];
  const float* Wk = (const float*)d_in[7];
  const float* bk = (const float*)d_in[8];
  const float* Wv = (const float*)d_in[9];
  const float* bv = (const float*)d_in[10];
  const float* Wo = (const float*)d_in[11];
  const float* bo = (const float*)d_in[12];

  char* ws = (char*)d_ws;
  short* WT   = (short*)(ws);                        // 4 x 512x512 bf16 = 2 MB
  short* qb   = (short*)(ws + ((size_t)2  << 20));   // [N,H,T,64] bf16 = 8 MB
  short* kb   = (short*)(ws + ((size_t)10 << 20));   // [N,H,T,64] bf16 = 8 MB
  short* vT   = (short*)(ws + ((size_t)18 << 20));   // [N,H,64,T] bf16 = 8 MB
  short* attn = (short*)(ws + ((size_t)26 << 20));   // [N,T,D]   bf16 = 8 MB
  float* outp  = (float*)d_out;
  float* pmean = outp + (size_t)NB * TT * DD;

  kt_transpose<<<dim3(16, 16, 4), dim3(32, 8), 0, stream>>>(Wq, Wk, Wv, Wo, WT);
  kt_proj<<<dim3(128, 8, 3), 256, 0, stream>>>(query, key_, value, WT, bq, bk, bv, qb, kb, vT);
  kt_attn<<<dim3(512), dim3(512), 0, stream>>>(qb, kb, vT, segms, mask, attn, pmean);
  kt_outproj<<<dim3(128, 8), 256, 0, stream>>>(attn, WT + (size_t)3 * DD * DD, bo, outp);
}

// Round 5
// 222.609 us; speedup vs baseline: 1.0920x; 1.0321x over previous
//
#include <hip/hip_runtime.h>
#include <hip/hip_bf16.h>
#include <hip/hip_fp16.h>
#include <cstdint>
#include <cstddef>

#define NB 8
#define TT 1024
#define DD 512
#define HH 8
#define DHD 64

using bf16x8 = __attribute__((ext_vector_type(8))) short;
using f32x4  = __attribute__((ext_vector_type(4))) float;

#define MFMA(a, b, c) __builtin_amdgcn_mfma_f32_16x16x32_bf16((a), (b), (c), 0, 0, 0)

__device__ __forceinline__ short f2bf(float f) {
  union { float f; uint32_t u; } x; x.f = f;
  uint32_t r = x.u + 0x7fffu + ((x.u >> 16) & 1u);
  return (short)(r >> 16);
}

// pack two floats into two bf16 (round-nearest-even) in one u32
__device__ __forceinline__ uint32_t pkbf(float a, float b) {
  union { float f; uint32_t u; } x, y; x.f = a; y.f = b;
  uint32_t ra = x.u + 0x7fffu + ((x.u >> 16) & 1u);
  uint32_t rb = y.u + 0x7fffu + ((y.u >> 16) & 1u);
  return (ra >> 16) | (rb & 0xffff0000u);
}

// ---------------- weight transpose + f32->bf16 ----------------
__global__ __launch_bounds__(256) void kt_transpose(
    const float* __restrict__ W0, const float* __restrict__ W1,
    const float* __restrict__ W2, const float* __restrict__ W3,
    short* __restrict__ WT)
{
  __shared__ float tile[32][33];
  int z = blockIdx.z;
  const float* W = (z == 0) ? W0 : (z == 1) ? W1 : (z == 2) ? W2 : W3;
  short* out = WT + (size_t)z * DD * DD;
  int tx = threadIdx.x, ty = threadIdx.y;  // (32, 8)
  int bx = blockIdx.x * 32, by = blockIdx.y * 32;
#pragma unroll
  for (int kq = 0; kq < 4; ++kq)
    tile[ty + kq * 8][tx] = W[(size_t)(by + ty + kq * 8) * DD + bx + tx];
  __syncthreads();
#pragma unroll
  for (int kq = 0; kq < 4; ++kq)
    out[(size_t)(bx + ty + kq * 8) * DD + by + tx] = f2bf(tile[tx][ty + kq * 8]);
}

// ---------------- QKV projection GEMM ----------------
// z: 0=Q (scaled by 1/8, layout [N,H,T,64]), 1=K ([N,H,T,64]), 2=V ([N,H,64,T])
__global__ __launch_bounds__(256) void kt_proj(
    const float* __restrict__ Xq, const float* __restrict__ Xk, const float* __restrict__ Xv,
    const short* __restrict__ WTall,
    const float* __restrict__ bq, const float* __restrict__ bk, const float* __restrict__ bv,
    short* __restrict__ qb, short* __restrict__ kb, short* __restrict__ vT)
{
  int z = blockIdx.z;
  const float* X    = (z == 0) ? Xq : (z == 1) ? Xk : Xv;
  const short* WT   = WTall + (size_t)z * DD * DD;
  const float* bias = (z == 0) ? bq : (z == 1) ? bk : bv;
  short* out        = (z == 0) ? qb : (z == 1) ? kb : vT;

  __shared__ alignas(16) short As[64][40];
  __shared__ alignas(16) short Bs[64][40];
  int tid = threadIdx.x;
  int w = tid >> 6, lane = tid & 63, g = lane >> 4, c16 = lane & 15;
  int m0 = blockIdx.x * 64, c0 = blockIdx.y * 64;
  int srow = tid >> 2, skg = (tid & 3) * 8;
  f32x4 acc[4] = {};

  for (int kk = 0; kk < DD; kk += 32) {
    const float* ap = X + (size_t)(m0 + srow) * DD + kk + skg;
    float4 a0 = *(const float4*)ap;
    float4 a1 = *(const float4*)(ap + 4);
    bf16x8 av;
    av[0] = f2bf(a0.x); av[1] = f2bf(a0.y); av[2] = f2bf(a0.z); av[3] = f2bf(a0.w);
    av[4] = f2bf(a1.x); av[5] = f2bf(a1.y); av[6] = f2bf(a1.z); av[7] = f2bf(a1.w);
    *(bf16x8*)&As[srow][skg] = av;
    *(bf16x8*)&Bs[srow][skg] = *(const bf16x8*)(WT + (size_t)(c0 + srow) * DD + kk + skg);
    __syncthreads();
    bf16x8 af = *(const bf16x8*)&As[w * 16 + c16][g * 8];
#pragma unroll
    for (int ct = 0; ct < 4; ++ct) {
      bf16x8 bfv = *(const bf16x8*)&Bs[ct * 16 + c16][g * 8];
      acc[ct] = MFMA(af, bfv, acc[ct]);
    }
    __syncthreads();
  }

#pragma unroll
  for (int ct = 0; ct < 4; ++ct) {
    int c = c0 + ct * 16 + c16;
    float bv_ = bias[c];
    int hh = c >> 6, dh = c & 63;
#pragma unroll
    for (int r = 0; r < 4; ++r) {
      int m = m0 + w * 16 + g * 4 + r;
      int n = m >> 10, t = m & 1023;
      float val = acc[ct][r] + bv_;
      if (z == 0) val *= 0.125f;  // fold score scaling into q
      size_t addr = (z < 2)
          ? ((((size_t)n * HH + hh) * TT + t) * DHD + dh)     // q,k: [N,H,T,64]
          : ((((size_t)n * HH + hh) * DHD + dh) * TT + t);    // v : [N,H,64,T]
      out[addr] = f2bf(val);
    }
  }
}

// ---------------- output projection GEMM ----------------
__global__ __launch_bounds__(256) void kt_outproj(
    const short* __restrict__ A, const short* __restrict__ WT,
    const float* __restrict__ bias, float* __restrict__ out)
{
  __shared__ alignas(16) short As[64][40];
  __shared__ alignas(16) short Bs[64][40];
  int tid = threadIdx.x;
  int w = tid >> 6, lane = tid & 63, g = lane >> 4, c16 = lane & 15;
  int m0 = blockIdx.x * 64, c0 = blockIdx.y * 64;
  int srow = tid >> 2, skg = (tid & 3) * 8;
  f32x4 acc[4] = {};

  for (int kk = 0; kk < DD; kk += 32) {
    *(bf16x8*)&As[srow][skg] = *(const bf16x8*)(A + (size_t)(m0 + srow) * DD + kk + skg);
    *(bf16x8*)&Bs[srow][skg] = *(const bf16x8*)(WT + (size_t)(c0 + srow) * DD + kk + skg);
    __syncthreads();
    bf16x8 af = *(const bf16x8*)&As[w * 16 + c16][g * 8];
#pragma unroll
    for (int ct = 0; ct < 4; ++ct) {
      bf16x8 bfv = *(const bf16x8*)&Bs[ct * 16 + c16][g * 8];
      acc[ct] = MFMA(af, bfv, acc[ct]);
    }
    __syncthreads();
  }

#pragma unroll
  for (int ct = 0; ct < 4; ++ct) {
    int c = c0 + ct * 16 + c16;
    float bv_ = bias[c];
#pragma unroll
    for (int r = 0; r < 4; ++r) {
      int m = m0 + w * 16 + g * 4 + r;
      out[(size_t)m * DD + c] = acc[ct][r] + bv_;
    }
  }
}

// ---------------- fused attention, v6 ----------------
// v5 macrostructure (8 waves x 128-k slice, swapped QK^T, union LDS,
// 2 barriers/head). Change: EXPLICIT REGISTER STAGING of K and V fragments
// with __launch_bounds__(512,1) so all 16 loads of each phase are in flight
// simultaneously (v5's 72-VGPR budget serialized them ~2-4 deep -> ~28K cyc
// per head-phase of exposed latency). V loads issued BEFORE softmax so their
// latency hides under softmax + barrier + combine.
__global__ __launch_bounds__(512, 1) void kt_attn(
    const short* __restrict__ qbuf, const short* __restrict__ kbuf, const short* __restrict__ vT,
    const float* __restrict__ segms, const int* __restrict__ mask,
    short* __restrict__ attn, float* __restrict__ pmean)
{
  int bx = blockIdx.x;
  int n = bx & 7, qt = bx >> 3;          // XCD-local batch
  int tid = threadIdx.x, w = tid >> 6, lane = tid & 63, g = lane >> 4, c16 = lane & 15;
  int kw = w * 128;

  // per-wave union region: pbuf short[16][136] (4352 B) | outred float[16][66] (4224 B)
  __shared__ alignas(16) char uni[8][4352];
  __shared__ alignas(16) float red_mT[16][8];
  __shared__ alignas(16) float red_sT[16][8];
  short (*pbuf)[136] = (short (*)[136])uni[w];
  float (*outw)[66]  = (float (*)[66])uni[w];

  // ---- hoist mask bits + segms (fp16 packed); h-invariant; vectorized ----
  // lane owns q-row (qt*16 + c16), k-cols kw + ct*16 + g*4 + {0..3}
  unsigned mm = 0u;
  __half2 sgp[8][2];
  float pm[8][4];
  uint32_t rowbase = ((uint32_t)(n * TT) + qt * 16 + c16) * TT + kw + g * 4;
#pragma unroll
  for (int ct = 0; ct < 8; ++ct) {
    int4   mv = *(const int4*)  &mask [rowbase + ct * 16];
    float4 sg = *(const float4*)&segms[rowbase + ct * 16];
    if (mv.x) mm |= 1u << (ct * 4 + 0);
    if (mv.y) mm |= 1u << (ct * 4 + 1);
    if (mv.z) mm |= 1u << (ct * 4 + 2);
    if (mv.w) mm |= 1u << (ct * 4 + 3);
    sgp[ct][0] = __floats2half2_rn(sg.x, sg.y);
    sgp[ct][1] = __floats2half2_rn(sg.z, sg.w);
    pm[ct][0] = 0.f; pm[ct][1] = 0.f; pm[ct][2] = 0.f; pm[ct][3] = 0.f;
  }

  for (int hh = 0; hh < HH; ++hh) {
    int h = (hh + qt) & 7;  // stagger heads across blocks
    const short* qp = qbuf + ((((size_t)n * HH + h) * TT) + qt * 16) * DHD;
    const short* kp = kbuf + (((size_t)n * HH + h) * TT) * DHD;
    const short* vp = vT   + (((size_t)n * HH + h) * DHD) * TT;

    bf16x8 aq0 = *(const bf16x8*)(qp + c16 * DHD + g * 8);
    bf16x8 aq1 = *(const bf16x8*)(qp + c16 * DHD + g * 8 + 32);

    // ---- stage ALL 16 K fragments into registers (16 loads in flight) ----
    bf16x8 kf0[8], kf1[8];
#pragma unroll
    for (int ct = 0; ct < 8; ++ct) {
      const short* kpp = kp + (size_t)(kw + ct * 16 + c16) * DHD + g * 8;
      kf0[ct] = *(const bf16x8*)kpp;
      kf1[ct] = *(const bf16x8*)(kpp + 32);
    }

    // ---- swapped QK^T: sc[ct][r] = S(q = c16, k = kw + ct*16 + g*4 + r) ----
    f32x4 sc[8];
    __builtin_amdgcn_s_setprio(1);
#pragma unroll
    for (int ct = 0; ct < 8; ++ct) {
      f32x4 a = {};
      a = MFMA(kf0[ct], aq0, a);
      a = MFMA(kf1[ct], aq1, a);
      sc[ct] = a;
    }
    __builtin_amdgcn_s_setprio(0);

    // ---- stage ALL 16 V fragments now; latency hides under softmax ----
    bf16x8 vf[16];
#pragma unroll
    for (int ks = 0; ks < 4; ++ks)
#pragma unroll
      for (int ct = 0; ct < 4; ++ct)
        vf[ks * 4 + ct] = *(const bf16x8*)(vp + (size_t)(ct * 16 + c16) * TT + kw + ks * 32 + g * 8);

    // ---- mask + in-lane row max + 2 shuffles ----
    float mx = -3e38f;
#pragma unroll
    for (int ct = 0; ct < 8; ++ct)
#pragma unroll
      for (int r = 0; r < 4; ++r) {
        float s = ((mm >> (ct * 4 + r)) & 1u) ? sc[ct][r] : -1e9f;
        sc[ct][r] = s;
        mx = fmaxf(mx, s);
      }
    mx = fmaxf(mx, __shfl_xor(mx, 16));
    mx = fmaxf(mx, __shfl_xor(mx, 32));

    // ---- exp with wave-local max (p<=1 safe) + in-lane sum + 2 shuffles ----
    float sm = 0.f;
#pragma unroll
    for (int ct = 0; ct < 8; ++ct)
#pragma unroll
      for (int r = 0; r < 4; ++r) {
        float p = __expf(sc[ct][r] - mx);
        sc[ct][r] = p;
        sm += p;
      }
    sm += __shfl_xor(sm, 16);
    sm += __shfl_xor(sm, 32);
    if (lane < 16) {
      red_mT[c16][w] = mx;
      red_sT[c16][w] = sm;
    }
    __syncthreads();  // barrier A: (m,S) ready; fences prev head's outw reads vs pbuf writes

    // ---- combine: scale_w = exp(m_w - m*) / Z ----
    f32x4 vm0 = *(const f32x4*)&red_mT[c16][0];
    f32x4 vm1 = *(const f32x4*)&red_mT[c16][4];
    f32x4 vs0 = *(const f32x4*)&red_sT[c16][0];
    f32x4 vs1 = *(const f32x4*)&red_sT[c16][4];
    float ms = fmaxf(fmaxf(fmaxf(vm0[0], vm0[1]), fmaxf(vm0[2], vm0[3])),
                     fmaxf(fmaxf(vm1[0], vm1[1]), fmaxf(vm1[2], vm1[3])));
    float Z = vs0[0] * __expf(vm0[0] - ms) + vs0[1] * __expf(vm0[1] - ms)
            + vs0[2] * __expf(vm0[2] - ms) + vs0[3] * __expf(vm0[3] - ms)
            + vs1[0] * __expf(vm1[0] - ms) + vs1[1] * __expf(vm1[1] - ms)
            + vs1[2] * __expf(vm1[2] - ms) + vs1[3] * __expf(vm1[3] - ms);
    float scl = __expf(mx - ms) / Z;

    // ---- probs = p*scale*segms ; accumulate pmean ; stash packed b64 ----
#pragma unroll
    for (int ct = 0; ct < 8; ++ct) {
      float2 s01 = __half22float2(sgp[ct][0]);
      float2 s23 = __half22float2(sgp[ct][1]);
      float p0 = sc[ct][0] * scl * s01.x;
      float p1 = sc[ct][1] * scl * s01.y;
      float p2 = sc[ct][2] * scl * s23.x;
      float p3 = sc[ct][3] * scl * s23.y;
      pm[ct][0] += p0; pm[ct][1] += p1; pm[ct][2] += p2; pm[ct][3] += p3;
      uint2 pk; pk.x = pkbf(p0, p1); pk.y = pkbf(p2, p3);
      *(uint2*)&pbuf[c16][ct * 16 + g * 4] = pk;
    }
    // no barrier: pbuf slice is wave-private (same-wave ds ordering)

    // ---- PV over this wave's 128-k slice (V already in registers) ----
    f32x4 oa[4] = {};
    __builtin_amdgcn_s_setprio(1);
#pragma unroll
    for (int ks = 0; ks < 4; ++ks) {
      bf16x8 pa = *(const bf16x8*)&pbuf[c16][ks * 32 + g * 8];
#pragma unroll
      for (int ct = 0; ct < 4; ++ct)
        oa[ct] = MFMA(pa, vf[ks * 4 + ct], oa[ct]);
    }
    __builtin_amdgcn_s_setprio(0);

    // overwrite own (dead) pbuf region with PV partials — wave-private
#pragma unroll
    for (int ct = 0; ct < 4; ++ct)
#pragma unroll
      for (int r = 0; r < 4; ++r)
        outw[g * 4 + r][ct * 16 + c16] = oa[ct][r];
    __syncthreads();  // barrier C: all partials ready

    // ---- cross-wave reduce (8 partials) + write attn[n][t][h*64+d] ----
    {
      int q = tid >> 5, dg = (tid & 31) * 2;
      float v0 = 0.f, v1 = 0.f;
#pragma unroll
      for (int wi = 0; wi < 8; ++wi) {
        float2 rd = *(const float2*)((const float*)uni[wi] + q * 66 + dg);
        v0 += rd.x;
        v1 += rd.y;
      }
      ushort2 st;
      st.x = (unsigned short)f2bf(v0);
      st.y = (unsigned short)f2bf(v1);
      *(ushort2*)(attn + ((size_t)(n * TT) + qt * 16 + q) * DD + h * DHD + dg) = st;
    }
    // next head's pbuf writes are fenced by barrier A of that head
  }

  // ---- write probs mean (1/H), vectorized float4 ----
#pragma unroll
  for (int ct = 0; ct < 8; ++ct) {
    float4 o;
    o.x = pm[ct][0] * 0.125f; o.y = pm[ct][1] * 0.125f;
    o.z = pm[ct][2] * 0.125f; o.w = pm[ct][3] * 0.125f;
    *(float4*)&pmean[rowbase + ct * 16] = o;
  }
}

extern "C" void kernel_launch(void* const* d_in, const int* in_sizes, int n_in,
                              void* d_out, int out_size, void* d_ws, size_t ws_size,
                              hipStream_t stream) {
  const float* query = (const float*)d_in[0];
  const float* key_  = (const float*)d_in[1];
  const float* value = (const float*)d_in[2];
  const float* segms = (const float*)d_in[3];
  const int*   mask  = (const int*)d_in[4];
  const float* Wq = (const float*)d_in[5];
  const float* bq = (const float*)d_in[6];
  const float* Wk = (const float*)d_in[7];
  const float* bk = (const float*)d_in[8];
  const float* Wv = (const float*)d_in[9];
  const float* bv = (const float*)d_in[10];
  const float* Wo = (const float*)d_in[11];
  const float* bo = (const float*)d_in[12];

  char* ws = (char*)d_ws;
  short* WT   = (short*)(ws);                        // 4 x 512x512 bf16 = 2 MB
  short* qb   = (short*)(ws + ((size_t)2  << 20));   // [N,H,T,64] bf16 = 8 MB
  short* kb   = (short*)(ws + ((size_t)10 << 20));   // [N,H,T,64] bf16 = 8 MB
  short* vT   = (short*)(ws + ((size_t)18 << 20));   // [N,H,64,T] bf16 = 8 MB
  short* attn = (short*)(ws + ((size_t)26 << 20));   // [N,T,D]   bf16 = 8 MB
  float* outp  = (float*)d_out;
  float* pmean = outp + (size_t)NB * TT * DD;

  kt_transpose<<<dim3(16, 16, 4), dim3(32, 8), 0, stream>>>(Wq, Wk, Wv, Wo, WT);
  kt_proj<<<dim3(128, 8, 3), 256, 0, stream>>>(query, key_, value, WT, bq, bk, bv, qb, kb, vT);
  kt_attn<<<dim3(512), dim3(512), 0, stream>>>(qb, kb, vT, segms, mask, attn, pmean);
  kt_outproj<<<dim3(128, 8), 256, 0, stream>>>(attn, WT + (size_t)3 * DD * DD, bo, outp);
}